// Round 1
// baseline (329.730 us; speedup 1.0000x reference)
//
#include <hip/hip_runtime.h>
#include <math.h>

#define BB 16
#define CC 256
#define HH 96
#define WW 96
#define GG 4
#define KK 3
#define CR 64   // C / RED

// ---------------- Kernel 1: 32x32 block-average pool -> pooled (B,C,3,3) ----
__global__ __launch_bounds__(256) void pool_kernel(const float* __restrict__ x,
                                                   float* __restrict__ pooled) {
    const int bc = blockIdx.x;                       // 0 .. B*C-1
    const float4* p4 = (const float4*)(x + (size_t)bc * (HH * WW));
    const int tid  = threadIdx.x;
    const int lane = tid & 63;
    const int wv   = tid >> 6;
    __shared__ float red[4];

    const int r_in = tid >> 3;   // 0..31  row inside a 32x32 block
    const int c4   = tid & 7;    // 0..7   float4 inside the 32-wide block

    #pragma unroll
    for (int bi = 0; bi < 3; ++bi) {
        #pragma unroll
        for (int bj = 0; bj < 3; ++bj) {
            const int row = bi * 32 + r_in;
            const int idx = row * 24 + bj * 8 + c4;  // 24 float4 per 96-float row
            float4 v = p4[idx];
            float s = v.x + v.y + v.z + v.w;
            #pragma unroll
            for (int off = 32; off > 0; off >>= 1) s += __shfl_down(s, off, 64);
            if (lane == 0) red[wv] = s;
            __syncthreads();
            if (tid == 0)
                pooled[bc * 9 + bi * 3 + bj] =
                    (red[0] + red[1] + red[2] + red[3]) * (1.0f / 1024.0f);
            __syncthreads();
        }
    }
}

// ---------------- Kernel 2: MLP + softmax(G) + mix -> weight (B,C,9), bias (B,C)
__global__ __launch_bounds__(256) void proj_kernel(
    const float* __restrict__ pooled,
    const float* __restrict__ w1, const float* __restrict__ b1,
    const float* __restrict__ bn_g, const float* __restrict__ bn_b,
    const float* __restrict__ bn_m, const float* __restrict__ bn_v,
    const float* __restrict__ w2, const float* __restrict__ b2,
    const float* __restrict__ w_k, const float* __restrict__ b_k,
    float* __restrict__ weight, float* __restrict__ bias) {
    const int b = blockIdx.x / 10;
    const int p = blockIdx.x % 10;   // 0..8 = pooled pixel, 9 = global mean
    const int tid = threadIdx.x;     // == channel c in the epilogue

    __shared__ float t[CC];
    __shared__ float hbuf[CR];
    __shared__ float hpart[256];

    if (p < 9) {
        t[tid] = pooled[(b * CC + tid) * 9 + p];
    } else {
        float s = 0.f;
        #pragma unroll
        for (int q = 0; q < 9; ++q) s += pooled[(b * CC + tid) * 9 + q];
        t[tid] = s * (1.0f / 9.0f);
    }
    __syncthreads();

    // h = w1 @ t  (64 outputs, 4 partial-threads each)
    const int o = tid & 63, part = tid >> 6;
    {
        const float* w1row = w1 + o * CC + part * 64;
        const float* tp = t + part * 64;
        float acc = 0.f;
        #pragma unroll
        for (int k = 0; k < 64; ++k) acc += w1row[k] * tp[k];
        hpart[tid] = acc;
    }
    __syncthreads();
    if (tid < 64) {
        float hsum = hpart[tid] + hpart[tid + 64] + hpart[tid + 128] +
                     hpart[tid + 192] + b1[tid];
        // BatchNorm (inference)
        float hn = (hsum - bn_m[tid]) * (bn_g[tid] * rsqrtf(bn_v[tid] + 1e-5f)) + bn_b[tid];
        // exact GELU
        hbuf[tid] = 0.5f * hn * (1.0f + erff(hn * 0.70710678118654752f));
    }
    __syncthreads();

    // out[j] for j = q*256 + tid  (q = group g, tid = channel c)
    float vals[4];
    #pragma unroll
    for (int q = 0; q < 4; ++q) {
        const int j = q * 256 + tid;
        const float* w2row = w2 + j * 64;
        float a = b2[j];
        #pragma unroll
        for (int o2 = 0; o2 < 64; ++o2) a += w2row[o2] * hbuf[o2];
        vals[q] = a;
    }
    // softmax over the 4 groups (thread-local)
    float m = fmaxf(fmaxf(vals[0], vals[1]), fmaxf(vals[2], vals[3]));
    float e[4], sum = 0.f;
    #pragma unroll
    for (int q = 0; q < 4; ++q) { e[q] = expf(vals[q] - m); sum += e[q]; }
    const float rinv = 1.0f / sum;

    if (p < 9) {
        float ws = 0.f;
        #pragma unroll
        for (int q = 0; q < 4; ++q)
            ws += (e[q] * rinv) * w_k[(q * CC + tid) * 9 + p];
        weight[(b * CC + tid) * 9 + p] = ws;
    } else {
        float bs = 0.f;
        #pragma unroll
        for (int q = 0; q < 4; ++q)
            bs += (e[q] * rinv) * b_k[q * CC + tid];
        bias[b * CC + tid] = bs;
    }
}

// ---------------- Kernel 3: dynamic depthwise 3x3 conv (SAME) + bias ---------
__global__ __launch_bounds__(256) void dwconv_kernel(
    const float* __restrict__ x, const float* __restrict__ weight,
    const float* __restrict__ bias, float* __restrict__ out) {
    const int bc = blockIdx.x;
    const float* plane = x + (size_t)bc * (HH * WW);
    float* oplane = out + (size_t)bc * (HH * WW);
    __shared__ __align__(16) float tile[HH * WW];
    const int tid = threadIdx.x;

    // stage plane into LDS (float4, coalesced)
    {
        const float4* p4 = (const float4*)plane;
        float4* t4 = (float4*)tile;
        #pragma unroll
        for (int i = 0; i < 9; ++i) t4[tid + 256 * i] = p4[tid + 256 * i];
    }
    // per-(b,c) kernel + bias (block-uniform)
    float wgt[9];
    #pragma unroll
    for (int k = 0; k < 9; ++k) wgt[k] = weight[bc * 9 + k];
    const float bs = bias[bc];
    __syncthreads();

    #pragma unroll 4
    for (int i = 0; i < 36; ++i) {
        const int p = tid + 256 * i;
        const int h = p / 96;
        const int w = p - h * 96;
        float acc = bs;
        #pragma unroll
        for (int dh = -1; dh <= 1; ++dh) {
            const int hh = h + dh;
            const bool hok = (unsigned)hh < 96u;
            #pragma unroll
            for (int dw = -1; dw <= 1; ++dw) {
                const int ww = w + dw;
                const bool ok = hok && ((unsigned)ww < 96u);
                float v = ok ? tile[hh * 96 + ww] : 0.0f;
                acc += wgt[(dh + 1) * 3 + (dw + 1)] * v;
            }
        }
        oplane[p] = acc;
    }
}

extern "C" void kernel_launch(void* const* d_in, const int* in_sizes, int n_in,
                              void* d_out, int out_size, void* d_ws, size_t ws_size,
                              hipStream_t stream) {
    const float* x    = (const float*)d_in[0];
    const float* w_k  = (const float*)d_in[1];
    const float* b_k  = (const float*)d_in[2];
    const float* w1   = (const float*)d_in[3];
    const float* b1   = (const float*)d_in[4];
    const float* bn_g = (const float*)d_in[5];
    const float* bn_b = (const float*)d_in[6];
    const float* bn_m = (const float*)d_in[7];
    const float* bn_v = (const float*)d_in[8];
    const float* w2   = (const float*)d_in[9];
    const float* b2   = (const float*)d_in[10];
    float* out = (float*)d_out;

    float* pooled = (float*)d_ws;                 // B*C*9 floats
    float* weight = pooled + BB * CC * 9;         // B*C*9 floats
    float* bias   = weight + BB * CC * 9;         // B*C   floats

    pool_kernel<<<BB * CC, 256, 0, stream>>>(x, pooled);
    proj_kernel<<<BB * 10, 256, 0, stream>>>(pooled, w1, b1, bn_g, bn_b, bn_m,
                                             bn_v, w2, b2, w_k, b_k, weight, bias);
    dwconv_kernel<<<BB * CC, 256, 0, stream>>>(x, weight, bias, out);
}

// Round 2
// 317.243 us; speedup vs baseline: 1.0394x; 1.0394x over previous
//
#include <hip/hip_runtime.h>
#include <math.h>

#define BB 16
#define CC 256
#define HH 96
#define WW 96
#define TS 104   // LDS tile row stride (floats): 96 data + halo, keeps float4 alignment

// ---------------- Kernel 1: 32x32 block-average pool -> pooled (B,C,3,3) ----
// All 9 loads issued up front (9x memory parallelism), one sync total.
__global__ __launch_bounds__(256) void pool_kernel(const float* __restrict__ x,
                                                   float* __restrict__ pooled) {
    const int bc = blockIdx.x;                       // 0 .. B*C-1
    const float4* p4 = (const float4*)(x + (size_t)bc * (HH * WW));
    const int tid  = threadIdx.x;
    const int lane = tid & 63;
    const int wv   = tid >> 6;
    const int r_in = tid >> 3;   // 0..31  row inside a 32x32 block
    const int c4   = tid & 7;    // 0..7   float4 inside the 32-wide block
    __shared__ float red[9][4];

    float s[9];
    #pragma unroll
    for (int bi = 0; bi < 3; ++bi)
        #pragma unroll
        for (int bj = 0; bj < 3; ++bj) {
            float4 v = p4[(bi * 32 + r_in) * 24 + bj * 8 + c4];
            s[bi * 3 + bj] = v.x + v.y + v.z + v.w;
        }

    #pragma unroll
    for (int k = 0; k < 9; ++k) {
        float t = s[k];
        #pragma unroll
        for (int off = 32; off; off >>= 1) t += __shfl_down(t, off, 64);
        if (lane == 0) red[k][wv] = t;
    }
    __syncthreads();
    if (tid < 9)
        pooled[bc * 9 + tid] =
            (red[tid][0] + red[tid][1] + red[tid][2] + red[tid][3]) * (1.0f / 1024.0f);
}

// ---------------- Kernel 2: MLP + softmax(G) + mix -> weight (B,C,9), bias (B,C)
__global__ __launch_bounds__(256) void proj_kernel(
    const float* __restrict__ pooled,
    const float* __restrict__ w1, const float* __restrict__ b1,
    const float* __restrict__ bn_g, const float* __restrict__ bn_b,
    const float* __restrict__ bn_m, const float* __restrict__ bn_v,
    const float* __restrict__ w2, const float* __restrict__ b2,
    const float* __restrict__ w_k, const float* __restrict__ b_k,
    float* __restrict__ weight, float* __restrict__ bias) {
    const int b = blockIdx.x / 10;
    const int p = blockIdx.x % 10;   // 0..8 = pooled pixel, 9 = global mean
    const int tid = threadIdx.x;     // == channel c in the epilogue

    __shared__ __align__(16) float t[CC];
    __shared__ __align__(16) float hbuf[64];
    __shared__ float hpart[256];

    if (p < 9) {
        t[tid] = pooled[(b * CC + tid) * 9 + p];
    } else {
        float s = 0.f;
        #pragma unroll
        for (int q = 0; q < 9; ++q) s += pooled[(b * CC + tid) * 9 + q];
        t[tid] = s * (1.0f / 9.0f);
    }
    __syncthreads();

    // h = w1 @ t  (64 outputs, 4 partial-threads each), float4 dots
    const int o = tid & 63, part = tid >> 6;
    {
        const float4* w1r = (const float4*)(w1 + o * CC + part * 64);
        const float4* tp  = (const float4*)(t + part * 64);
        float acc = 0.f;
        #pragma unroll
        for (int k = 0; k < 16; ++k) {
            float4 a = w1r[k], v = tp[k];
            acc += a.x * v.x + a.y * v.y + a.z * v.z + a.w * v.w;
        }
        hpart[tid] = acc;
    }
    __syncthreads();
    if (tid < 64) {
        float hsum = hpart[tid] + hpart[tid + 64] + hpart[tid + 128] +
                     hpart[tid + 192] + b1[tid];
        float hn = (hsum - bn_m[tid]) * (bn_g[tid] * rsqrtf(bn_v[tid] + 1e-5f)) + bn_b[tid];
        hbuf[tid] = 0.5f * hn * (1.0f + erff(hn * 0.70710678118654752f));
    }
    __syncthreads();

    float vals[4];
    #pragma unroll
    for (int q = 0; q < 4; ++q) {
        const int j = q * 256 + tid;
        const float4* w2r = (const float4*)(w2 + j * 64);
        const float4* hb  = (const float4*)hbuf;
        float a = b2[j];
        #pragma unroll
        for (int k = 0; k < 16; ++k) {
            float4 wv = w2r[k], hv = hb[k];
            a += wv.x * hv.x + wv.y * hv.y + wv.z * hv.z + wv.w * hv.w;
        }
        vals[q] = a;
    }
    float m = fmaxf(fmaxf(vals[0], vals[1]), fmaxf(vals[2], vals[3]));
    float e[4], sum = 0.f;
    #pragma unroll
    for (int q = 0; q < 4; ++q) { e[q] = expf(vals[q] - m); sum += e[q]; }
    const float rinv = 1.0f / sum;

    if (p < 9) {
        float ws = 0.f;
        #pragma unroll
        for (int q = 0; q < 4; ++q)
            ws += (e[q] * rinv) * w_k[(q * CC + tid) * 9 + p];
        weight[(b * CC + tid) * 9 + p] = ws;
    } else {
        float bs = 0.f;
        #pragma unroll
        for (int q = 0; q < 4; ++q)
            bs += (e[q] * rinv) * b_k[q * CC + tid];
        bias[b * CC + tid] = bs;
    }
}

// ---------------- Kernel 3: dynamic depthwise 3x3 conv (SAME) + bias ---------
// Halo tile (98 rows x TS stride, data at [r+1][4+w]) -> branch-free inner loop.
// Each thread computes strips of 4 consecutive pixels: 3x(b128 + 2 b32) LDS
// reads per strip instead of 36 scalar reads.
__global__ __launch_bounds__(256) void dwconv_kernel(
    const float* __restrict__ x, const float* __restrict__ weight,
    const float* __restrict__ bias, float* __restrict__ out) {
    const int bc = blockIdx.x;
    const float* plane = x + (size_t)bc * (HH * WW);
    float* oplane = out + (size_t)bc * (HH * WW);
    __shared__ __align__(16) float tile[98 * TS];
    const int tid = threadIdx.x;

    // zero only the halo cells that the stencil can touch
    if (tid < 98) {
        tile[tid * TS + 3]   = 0.f;   // left halo col (c = -1)
        tile[tid * TS + 100] = 0.f;   // right halo col (c = 96)
        tile[3 + tid]            = 0.f;  // top halo row (h = -1), cols -1..96
        tile[97 * TS + 3 + tid]  = 0.f;  // bottom halo row (h = 96)
    }

    // per-(b,c) kernel + bias (block-uniform)
    float wgt[9];
    #pragma unroll
    for (int k = 0; k < 9; ++k) wgt[k] = weight[bc * 9 + k];
    const float bs = bias[bc];

    // stage plane into halo tile (float4, all 16B-aligned)
    {
        const float4* p4 = (const float4*)plane;
        float4* t4 = (float4*)tile;
        #pragma unroll
        for (int i = 0; i < 9; ++i) {
            const int idx4 = tid + 256 * i;          // 0..2303
            const int r = idx4 / 24;                 // 24 float4 per 96-wide row
            const int c4 = idx4 - r * 24;
            t4[(r + 1) * (TS / 4) + 1 + c4] = p4[idx4];
        }
    }
    __syncthreads();

    #pragma unroll
    for (int j = 0; j < 9; ++j) {
        const int s = tid + 256 * j;     // strip id, 0..2303
        const int h = s / 24;            // output row 0..95
        const int wq = s - h * 24;       // strip within row
        const int cb = 4 + 4 * wq;       // tile col of first pixel
        float4 acc = {bs, bs, bs, bs};
        #pragma unroll
        for (int r = 0; r < 3; ++r) {
            const int a = (h + r) * TS + cb;   // halo row h+r = input row h-1+r
            const float4 m = *(const float4*)(tile + a);
            const float L = tile[a - 1];
            const float R = tile[a + 4];
            const float wl = wgt[r * 3 + 0], wc = wgt[r * 3 + 1], wr = wgt[r * 3 + 2];
            acc.x += wl * L   + wc * m.x + wr * m.y;
            acc.y += wl * m.x + wc * m.y + wr * m.z;
            acc.z += wl * m.y + wc * m.z + wr * m.w;
            acc.w += wl * m.z + wc * m.w + wr * R;
        }
        *(float4*)(oplane + 4 * s) = acc;
    }
}

extern "C" void kernel_launch(void* const* d_in, const int* in_sizes, int n_in,
                              void* d_out, int out_size, void* d_ws, size_t ws_size,
                              hipStream_t stream) {
    const float* x    = (const float*)d_in[0];
    const float* w_k  = (const float*)d_in[1];
    const float* b_k  = (const float*)d_in[2];
    const float* w1   = (const float*)d_in[3];
    const float* b1   = (const float*)d_in[4];
    const float* bn_g = (const float*)d_in[5];
    const float* bn_b = (const float*)d_in[6];
    const float* bn_m = (const float*)d_in[7];
    const float* bn_v = (const float*)d_in[8];
    const float* w2   = (const float*)d_in[9];
    const float* b2   = (const float*)d_in[10];
    float* out = (float*)d_out;

    float* pooled = (float*)d_ws;                 // B*C*9 floats
    float* weight = pooled + BB * CC * 9;         // B*C*9 floats
    float* bias   = weight + BB * CC * 9;         // B*C   floats

    pool_kernel<<<BB * CC, 256, 0, stream>>>(x, pooled);
    proj_kernel<<<BB * 10, 256, 0, stream>>>(pooled, w1, b1, bn_g, bn_b, bn_m,
                                             bn_v, w2, b2, w_k, b_k, weight, bias);
    dwconv_kernel<<<BB * CC, 256, 0, stream>>>(x, weight, bias, out);
}

// Round 4
// 310.110 us; speedup vs baseline: 1.0633x; 1.0230x over previous
//
#include <hip/hip_runtime.h>
#include <math.h>

#define BB 16
#define CC 256
#define HH 96
#define WW 96
#define TS 104   // LDS tile row stride (floats): 96 data + halo, keeps float4 alignment

typedef float floatx4 __attribute__((ext_vector_type(4)));  // native vec for nontemporal store

// ---------------- Kernel 1: 32x32 block-average pool -> pooled (B,C,3,3) ----
// All 9 loads issued up front (9x memory parallelism), one sync total.
__global__ __launch_bounds__(256) void pool_kernel(const float* __restrict__ x,
                                                   float* __restrict__ pooled) {
    const int bc = blockIdx.x;                       // 0 .. B*C-1
    const float4* p4 = (const float4*)(x + (size_t)bc * (HH * WW));
    const int tid  = threadIdx.x;
    const int lane = tid & 63;
    const int wv   = tid >> 6;
    const int r_in = tid >> 3;   // 0..31  row inside a 32x32 block
    const int c4   = tid & 7;    // 0..7   float4 inside the 32-wide block
    __shared__ float red[9][4];

    float s[9];
    #pragma unroll
    for (int bi = 0; bi < 3; ++bi)
        #pragma unroll
        for (int bj = 0; bj < 3; ++bj) {
            float4 v = p4[(bi * 32 + r_in) * 24 + bj * 8 + c4];
            s[bi * 3 + bj] = v.x + v.y + v.z + v.w;
        }

    #pragma unroll
    for (int k = 0; k < 9; ++k) {
        float t = s[k];
        #pragma unroll
        for (int off = 32; off; off >>= 1) t += __shfl_down(t, off, 64);
        if (lane == 0) red[k][wv] = t;
    }
    __syncthreads();
    if (tid < 9)
        pooled[bc * 9 + tid] =
            (red[tid][0] + red[tid][1] + red[tid][2] + red[tid][3]) * (1.0f / 1024.0f);
}

// ---------------- Kernel 2: MLP + softmax(G) + mix -> weight (B,C,9), bias (B,C)
__global__ __launch_bounds__(256) void proj_kernel(
    const float* __restrict__ pooled,
    const float* __restrict__ w1, const float* __restrict__ b1,
    const float* __restrict__ bn_g, const float* __restrict__ bn_b,
    const float* __restrict__ bn_m, const float* __restrict__ bn_v,
    const float* __restrict__ w2, const float* __restrict__ b2,
    const float* __restrict__ w_k, const float* __restrict__ b_k,
    float* __restrict__ weight, float* __restrict__ bias) {
    const int b = blockIdx.x / 10;
    const int p = blockIdx.x % 10;   // 0..8 = pooled pixel, 9 = global mean
    const int tid = threadIdx.x;     // == channel c in the epilogue

    __shared__ __align__(16) float t[CC];
    __shared__ __align__(16) float hbuf[64];
    __shared__ float hpart[256];

    if (p < 9) {
        t[tid] = pooled[(b * CC + tid) * 9 + p];
    } else {
        float s = 0.f;
        #pragma unroll
        for (int q = 0; q < 9; ++q) s += pooled[(b * CC + tid) * 9 + q];
        t[tid] = s * (1.0f / 9.0f);
    }
    __syncthreads();

    // h = w1 @ t  (64 outputs, 4 partial-threads each), float4 dots
    const int o = tid & 63, part = tid >> 6;
    {
        const float4* w1r = (const float4*)(w1 + o * CC + part * 64);
        const float4* tp  = (const float4*)(t + part * 64);
        float acc = 0.f;
        #pragma unroll
        for (int k = 0; k < 16; ++k) {
            float4 a = w1r[k], v = tp[k];
            acc += a.x * v.x + a.y * v.y + a.z * v.z + a.w * v.w;
        }
        hpart[tid] = acc;
    }
    __syncthreads();
    if (tid < 64) {
        float hsum = hpart[tid] + hpart[tid + 64] + hpart[tid + 128] +
                     hpart[tid + 192] + b1[tid];
        float hn = (hsum - bn_m[tid]) * (bn_g[tid] * rsqrtf(bn_v[tid] + 1e-5f)) + bn_b[tid];
        hbuf[tid] = 0.5f * hn * (1.0f + erff(hn * 0.70710678118654752f));
    }
    __syncthreads();

    float vals[4];
    #pragma unroll
    for (int q = 0; q < 4; ++q) {
        const int j = q * 256 + tid;
        const float4* w2r = (const float4*)(w2 + j * 64);
        const float4* hb  = (const float4*)hbuf;
        float a = b2[j];
        #pragma unroll
        for (int k = 0; k < 16; ++k) {
            float4 wv = w2r[k], hv = hb[k];
            a += wv.x * hv.x + wv.y * hv.y + wv.z * hv.z + wv.w * hv.w;
        }
        vals[q] = a;
    }
    float m = fmaxf(fmaxf(vals[0], vals[1]), fmaxf(vals[2], vals[3]));
    float e[4], sum = 0.f;
    #pragma unroll
    for (int q = 0; q < 4; ++q) { e[q] = expf(vals[q] - m); sum += e[q]; }
    const float rinv = 1.0f / sum;

    if (p < 9) {
        float ws = 0.f;
        #pragma unroll
        for (int q = 0; q < 4; ++q)
            ws += (e[q] * rinv) * w_k[(q * CC + tid) * 9 + p];
        weight[(b * CC + tid) * 9 + p] = ws;
    } else {
        float bs = 0.f;
        #pragma unroll
        for (int q = 0; q < 4; ++q)
            bs += (e[q] * rinv) * b_k[q * CC + tid];
        bias[b * CC + tid] = bs;
    }
}

// ---------------- Kernel 3: dynamic depthwise 3x3 conv (SAME) + bias ---------
// Halo tile (98 rows x TS stride, data at [r+1][4+w]). Each thread computes a
// 4x4 pixel patch: 6x(b128 + 2 b32) LDS reads per 16 pixels (~8.9 cyc/px vs
// 17.7 for strip-of-4), leaving the kernel HBM-write-bound. Output stores are
// nontemporal (out is never re-read; keep x resident in L2/L3 instead).
__global__ __launch_bounds__(256) void dwconv_kernel(
    const float* __restrict__ x, const float* __restrict__ weight,
    const float* __restrict__ bias, float* __restrict__ out) {
    const int bc = blockIdx.x;
    const float* plane = x + (size_t)bc * (HH * WW);
    float* oplane = out + (size_t)bc * (HH * WW);
    __shared__ __align__(16) float tile[98 * TS];
    const int tid = threadIdx.x;

    // zero only the halo cells the stencil can touch
    if (tid < 98) {
        tile[tid * TS + 3]   = 0.f;      // left halo col (c = -1)
        tile[tid * TS + 100] = 0.f;      // right halo col (c = 96)
        tile[3 + tid]            = 0.f;  // top halo row (h = -1), cols -1..96
        tile[97 * TS + 3 + tid]  = 0.f;  // bottom halo row (h = 96)
    }

    // per-(b,c) kernel + bias (block-uniform)
    float wgt[9];
    #pragma unroll
    for (int k = 0; k < 9; ++k) wgt[k] = weight[bc * 9 + k];
    const float bs = bias[bc];

    // stage plane into halo tile (float4, all 16B-aligned)
    {
        const float4* p4 = (const float4*)plane;
        float4* t4 = (float4*)tile;
        #pragma unroll
        for (int i = 0; i < 9; ++i) {
            const int idx4 = tid + 256 * i;          // 0..2303
            const int r = idx4 / 24;                 // 24 float4 per 96-wide row
            const int c4 = idx4 - r * 24;
            t4[(r + 1) * (TS / 4) + 1 + c4] = p4[idx4];
        }
    }
    __syncthreads();

    // 4x4 patches: 24x24 = 576 per plane
    #pragma unroll
    for (int j = 0; j < 3; ++j) {
        const int pidx = tid + 256 * j;
        if (pidx < 576) {
            const int pr = pidx / 24;        // patch row 0..23
            const int pc = pidx - pr * 24;   // patch col 0..23
            const int h0 = pr * 4;           // first output row
            const int cb = 4 + pc * 4;       // tile col of first pixel

            // input rows h0-1 .. h0+4 = tile rows h0 .. h0+5
            float4 m[6]; float L[6], R[6];
            #pragma unroll
            for (int r = 0; r < 6; ++r) {
                const int a = (h0 + r) * TS + cb;
                m[r] = *(const float4*)(tile + a);
                L[r] = tile[a - 1];
                R[r] = tile[a + 4];
            }
            #pragma unroll
            for (int orow = 0; orow < 4; ++orow) {
                floatx4 acc = {bs, bs, bs, bs};
                #pragma unroll
                for (int r = 0; r < 3; ++r) {
                    const int rr = orow + r;
                    const float wl = wgt[r * 3 + 0], wc = wgt[r * 3 + 1],
                                wr = wgt[r * 3 + 2];
                    acc.x += wl * L[rr]   + wc * m[rr].x + wr * m[rr].y;
                    acc.y += wl * m[rr].x + wc * m[rr].y + wr * m[rr].z;
                    acc.z += wl * m[rr].y + wc * m[rr].z + wr * m[rr].w;
                    acc.w += wl * m[rr].z + wc * m[rr].w + wr * R[rr];
                }
                __builtin_nontemporal_store(
                    acc, (floatx4*)(oplane + (h0 + orow) * 96 + (cb - 4)));
            }
        }
    }
}

extern "C" void kernel_launch(void* const* d_in, const int* in_sizes, int n_in,
                              void* d_out, int out_size, void* d_ws, size_t ws_size,
                              hipStream_t stream) {
    const float* x    = (const float*)d_in[0];
    const float* w_k  = (const float*)d_in[1];
    const float* b_k  = (const float*)d_in[2];
    const float* w1   = (const float*)d_in[3];
    const float* b1   = (const float*)d_in[4];
    const float* bn_g = (const float*)d_in[5];
    const float* bn_b = (const float*)d_in[6];
    const float* bn_m = (const float*)d_in[7];
    const float* bn_v = (const float*)d_in[8];
    const float* w2   = (const float*)d_in[9];
    const float* b2   = (const float*)d_in[10];
    float* out = (float*)d_out;

    float* pooled = (float*)d_ws;                 // B*C*9 floats
    float* weight = pooled + BB * CC * 9;         // B*C*9 floats
    float* bias   = weight + BB * CC * 9;         // B*C   floats

    pool_kernel<<<BB * CC, 256, 0, stream>>>(x, pooled);
    proj_kernel<<<BB * 10, 256, 0, stream>>>(pooled, w1, b1, bn_g, bn_b, bn_m,
                                             bn_v, w2, b2, w_k, b_k, weight, bias);
    dwconv_kernel<<<BB * CC, 256, 0, stream>>>(x, weight, bias, out);
}